// Round 14
// baseline (219.232 us; speedup 1.0000x reference)
//
#include <hip/hip_runtime.h>

typedef _Float16 f16;
typedef _Float16 f16x8 __attribute__((ext_vector_type(8)));
typedef float    f32x4 __attribute__((ext_vector_type(4)));

#define HO 62
#define WO 62
#define SLICE 2896   // 2880 + 16 zeroed pad f16 (RECSZ=16 layout)

// ---------- A: parallel prep (6 blocks x 64) ----------
__global__ __launch_bounds__(64) void kan_prep_fast(
    const float* __restrict__ bw, const float* __restrict__ sw,
    const float* __restrict__ sc, f16x8* __restrict__ ws)
{
    const int lane = threadIdx.x;
    const int q    = blockIdx.x;         // 0..5 = ki*2+kjp
    const int ki   = q >> 1;
    const int kjp  = q & 1;
    const int nn   = lane & 15;
    const int kb   = lane >> 4;
    f16x8 bf;
    #pragma unroll
    for (int e = 0; e < 8; ++e) {
        const int k    = kb * 8 + e;
        const int kj   = kjp * 2 + (k >> 4);
        const int slot = k & 15;
        float wv = 0.0f;
        if (nn < 8 && kj < 3 && slot < 9) {
            const int kk = ki * 3 + kj;
            wv = (slot == 0) ? bw[nn * 9 + kk]
                             : sw[(nn * 9 + kk) * 8 + (slot - 1)] * sc[nn * 9 + kk];
        }
        bf[e] = (f16)wv;
    }
    ws[q * 64 + lane] = bf;
}

// ---------- shared body pieces ----------
__device__ __forceinline__ void stage1_v2(f16* __restrict__ wfeat,
    const float* __restrict__ xp, int r0, int c0, int lane,
    float g0, float inv_h)
{
    #pragma unroll
    for (int it = 0; it < 3; ++it) {
        const int p = it * 64 + lane;
        if (p < 180) {
            const int row = p / 18;
            const int col = p - row * 18;
            int gy = r0 + row; gy = (gy < 64) ? gy : 63;
            int gx = c0 + col; gx = (gx < 64) ? gx : 63;
            const float xv = xp[gy * 64 + gx];

            const float si = xv / (1.0f + __expf(-xv));
            const float u  = (xv - g0) * inv_h;
            int j = (int)floorf(u);
            j = (j < 3) ? 3 : ((j > 7) ? 7 : j);
            const float tt  = u - (float)j;
            const float omt = 1.0f - tt;
            const float t2  = tt * tt;
            const float t3  = t2 * tt;
            const float c6  = 1.0f / 6.0f;
            const float bv0 = omt * omt * omt * c6;
            const float bv1 = (3.0f * t3 - 6.0f * t2 + 4.0f) * c6;
            const float bv2 = (-3.0f * t3 + 3.0f * t2 + 3.0f * tt + 1.0f) * c6;
            const float bv3 = t3 * c6;

            f16x8 r0v, r1v;
            r0v[0] = (f16)si;
            #pragma unroll
            for (int f = 1; f < 8; ++f) {
                float val = 0.0f;
                val = (f == j - 2) ? bv0 : val;
                val = (f == j - 1) ? bv1 : val;
                val = (f == j)     ? bv2 : val;
                val = (f == j + 1) ? bv3 : val;
                r0v[f] = (f16)val;
            }
            r1v[0] = (f16)((8 == j + 1) ? bv3 : 0.0f);
            #pragma unroll
            for (int f = 1; f < 8; ++f) r1v[f] = (f16)0.f;

            f16* fp = &wfeat[p * 16];
            *(f16x8*)fp       = r0v;
            *(f16x8*)(fp + 8) = r1v;
        }
    }
}

__device__ __forceinline__ void stage2_run(
    const f16* __restrict__ wfeat, const f16x8 bfrag[3][2],
    float* __restrict__ dst, int plane, int r0, int c0,
    int lane, int aBase)
{
    const int mI = lane & 15;
    const int kb = lane >> 4;
    const int nn = mI;
    f16x8 af[3][2];
    #pragma unroll
    for (int kjp = 0; kjp < 2; ++kjp) {
        af[0][kjp] = *(const f16x8*)&wfeat[aBase + kjp * 32 + 0 * 288];
        af[1][kjp] = *(const f16x8*)&wfeat[aBase + kjp * 32 + 1 * 288];
    }
    #pragma unroll
    for (int i = 0; i < 8; ++i) {
        #pragma unroll
        for (int kjp = 0; kjp < 2; ++kjp)
            af[(i + 2) % 3][kjp] =
                *(const f16x8*)&wfeat[aBase + kjp * 32 + (i + 2) * 288];
        f32x4 acc = {0.f, 0.f, 0.f, 0.f};
        #pragma unroll
        for (int ki = 0; ki < 3; ++ki)
            #pragma unroll
            for (int kjp = 0; kjp < 2; ++kjp)
                acc = __builtin_amdgcn_mfma_f32_16x16x32_f16(
                          af[(i + ki) % 3][kjp], bfrag[ki][kjp], acc, 0, 0, 0);
        const int ho = r0 + i;
        if (nn < 8 && ho < HO) {
            const int cb = c0 + kb * 4;
            float* po = dst + ((size_t)(plane * 8 + nn) * (HO * WO)) + ho * WO + cb;
            if (cb + 3 < WO) {
                float2 lo = {acc[0], acc[1]};
                float2 hi = {acc[2], acc[3]};
                *(float2*)po       = lo;
                *(float2*)(po + 2) = hi;
            } else {
                #pragma unroll
                for (int q = 0; q < 4; ++q)
                    if (cb + q < WO) po[q] = acc[q];
            }
        }
    }
}

// ---------- B: production main (single pass -> out) ----------
__global__ __launch_bounds__(256, 4) void kan_main(
    const float* __restrict__ x, const float* __restrict__ grid_,
    const f16x8* __restrict__ ws, float* __restrict__ out)
{
    __shared__ __align__(16) f16 feat[4 * SLICE];
    const int tid  = threadIdx.x;
    const int lane = tid & 63;
    const int w    = tid >> 6;
    f16* wfeat = &feat[w * SLICE];

    const int unit  = blockIdx.x * 4 + w;
    const int plane = unit >> 5;
    const int chunk = (unit >> 2) & 7;
    const int s     = unit & 3;
    const int r0    = chunk * 8;
    const int c0    = s * 16;

    f16x8 bfrag[3][2];
    #pragma unroll
    for (int q = 0; q < 6; ++q)
        bfrag[q >> 1][q & 1] = ws[q * 64 + lane];

    if (lane < 2)
        *(f16x8*)&wfeat[2880 + lane * 8] = (f16x8){(f16)0.f,(f16)0.f,(f16)0.f,(f16)0.f,
                                                   (f16)0.f,(f16)0.f,(f16)0.f,(f16)0.f};

    const float g0    = grid_[0];
    const float inv_h = 1.0f / (grid_[1] - grid_[0]);
    const float* xp   = x + (size_t)plane * 4096;

    stage1_v2(wfeat, xp, r0, c0, lane, g0, inv_h);

    const int mI    = lane & 15;
    const int kb    = lane >> 4;
    const int aBase = (mI + (kb >> 1)) * 16 + (kb & 1) * 8;
    stage2_run(wfeat, bfrag, out, plane, r0, c0, lane, aBase);
}

// ---------- C: full-main rep probe (x8 -> scratch), setup inside loop ----------
__global__ __launch_bounds__(256, 4) void kan_main_rep(
    const float* __restrict__ x, const float* __restrict__ grid_,
    const f16x8* __restrict__ ws, float* __restrict__ wsf)
{
    __shared__ __align__(16) f16 feat[4 * SLICE];
    const int tid  = threadIdx.x;
    const int lane = tid & 63;
    const int w    = tid >> 6;
    f16* wfeat = &feat[w * SLICE];

    const int unit  = blockIdx.x * 4 + w;
    const int plane = unit >> 5;
    const int chunk = (unit >> 2) & 7;
    const int s     = unit & 3;
    const int r0    = chunk * 8;
    const int c0    = s * 16;

    const float g0    = grid_[0];
    const float inv_h = 1.0f / (grid_[1] - grid_[0]);

    const int mI    = lane & 15;
    const int kb    = lane >> 4;
    const int aBase = (mI + (kb >> 1)) * 16 + (kb & 1) * 8;

    #pragma unroll 1
    for (int rep = 0; rep < 8; ++rep) {
        int woff = 0, xoff = 0;
        asm volatile("" : "+v"(woff), "+v"(xoff));   // re-issue setup each rep
        const f16x8* wsq = ws + woff;
        const float* xp  = x + (size_t)plane * 4096 + xoff;

        f16x8 bfrag[3][2];
        #pragma unroll
        for (int q = 0; q < 6; ++q)
            bfrag[q >> 1][q & 1] = wsq[q * 64 + lane];

        if (lane < 2)
            *(f16x8*)&wfeat[2880 + lane * 8] = (f16x8){(f16)0.f,(f16)0.f,(f16)0.f,(f16)0.f,
                                                       (f16)0.f,(f16)0.f,(f16)0.f,(f16)0.f};

        stage1_v2(wfeat, xp, r0, c0, lane, g0, inv_h);
        stage2_run(wfeat, bfrag, wsf, plane, r0, c0, lane, aBase);
    }
}

// ---------- D: stage2-only rep probe (x16 -> scratch) ----------
__global__ __launch_bounds__(256, 4) void kan_stage2_rep(
    const f16x8* __restrict__ ws, float* __restrict__ wsf)
{
    __shared__ __align__(16) f16 feat[4 * SLICE];   // read uninitialized: timing-only
    const int tid  = threadIdx.x;
    const int lane = tid & 63;
    const int w    = tid >> 6;
    f16* wfeat = &feat[w * SLICE];

    const int unit  = blockIdx.x * 4 + w;
    const int plane = unit >> 5;
    const int chunk = (unit >> 2) & 7;
    const int s     = unit & 3;
    const int r0    = chunk * 8;
    const int c0    = s * 16;

    f16x8 bfrag[3][2];
    #pragma unroll
    for (int q = 0; q < 6; ++q)
        bfrag[q >> 1][q & 1] = ws[q * 64 + lane];

    const int mI = lane & 15;
    const int kb = lane >> 4;

    #pragma unroll 1
    for (int rep = 0; rep < 16; ++rep) {
        int aBase = (mI + (kb >> 1)) * 16 + (kb & 1) * 8;
        asm volatile("" : "+v"(aBase));              // re-issue ds_reads each rep
        stage2_run(wfeat, bfrag, wsf, plane, r0, c0, lane, aBase);
    }
}

extern "C" void kernel_launch(void* const* d_in, const int* in_sizes, int n_in,
                              void* d_out, int out_size, void* d_ws, size_t ws_size,
                              hipStream_t stream) {
    const float* x    = (const float*)d_in[0];
    const float* grid = (const float*)d_in[1];
    const float* bw   = (const float*)d_in[2];
    const float* sw   = (const float*)d_in[3];
    const float* sc   = (const float*)d_in[4];
    float* out = (float*)d_out;
    f16x8* ws  = (f16x8*)d_ws;
    float* wsf = (float*)d_ws + 4096;      // scratch sink, 16 KB past ws

    kan_prep_fast<<<6, 64, 0, stream>>>(bw, sw, sc, ws);          // A
    kan_main<<<2048, 256, 0, stream>>>(x, grid, ws, out);         // B (production)
    kan_main_rep<<<2048, 256, 0, stream>>>(x, grid, ws, wsf);     // C (x8 probe)
    kan_stage2_rep<<<2048, 256, 0, stream>>>(ws, wsf);            // D (x16 probe)
}

// Round 15
// 80.419 us; speedup vs baseline: 2.7261x; 2.7261x over previous
//
#include <hip/hip_runtime.h>

typedef _Float16 f16;
typedef _Float16 f16x8 __attribute__((ext_vector_type(8)));
typedef float    f32x4 __attribute__((ext_vector_type(4)));

#define HO 62
#define WO 62
#define SLICE 2896   // 2880 + 16 zeroed pad f16 (RECSZ=16 layout)

// ---------- prep: per-lane MFMA B-fragment image (6 blocks x 64, ~2 us) ----------
// ws[q*64 + lane], q = ki*2 + kjp. Main loads it as 6 coalesced dwordx4.
__global__ __launch_bounds__(64) void kan_prep_fast(
    const float* __restrict__ bw, const float* __restrict__ sw,
    const float* __restrict__ sc, f16x8* __restrict__ ws)
{
    const int lane = threadIdx.x;
    const int q    = blockIdx.x;         // 0..5 = ki*2+kjp
    const int ki   = q >> 1;
    const int kjp  = q & 1;
    const int nn   = lane & 15;
    const int kb   = lane >> 4;
    f16x8 bf;
    #pragma unroll
    for (int e = 0; e < 8; ++e) {
        const int k    = kb * 8 + e;
        const int kj   = kjp * 2 + (k >> 4);
        const int slot = k & 15;
        float wv = 0.0f;
        if (nn < 8 && kj < 3 && slot < 9) {
            const int kk = ki * 3 + kj;
            wv = (slot == 0) ? bw[nn * 9 + kk]
                             : sw[(nn * 9 + kk) * 8 + (slot - 1)] * sc[nn * 9 + kk];
        }
        bf[e] = (f16)wv;
    }
    ws[q * 64 + lane] = bf;
}

// ---------- main: barrier-free wave-private MFMA KAN conv (~8 us) ----------
// 2048 blocks x 256 thr (4 independent waves). Wave unit = (plane, row-chunk,
// col-tile). Stage 1: branchless f16 feature-record build (slot0 = silu,
// slots1..8 = uniform cubic B-spline bases, 4 nonzero), 2x ds_write_b128 per
// pixel (NO scatter writes - R12 A/B showed scatter cost ~2x). Stage 2:
// 8 output rows x 16 cols x 8 convs via 6 MFMA 16x16x32_f16 per row with
// rolling A-fragment reuse. No __syncthreads (wave reads only its own LDS).
__global__ __launch_bounds__(256, 4) void kan_main(
    const float* __restrict__ x,     // (256, 64, 64)
    const float* __restrict__ grid_, // (9, 12) uniform knots
    const f16x8* __restrict__ ws,    // prep output
    float* __restrict__ out)         // (256*8, 62, 62)
{
    __shared__ __align__(16) f16 feat[4 * SLICE];
    const int tid  = threadIdx.x;
    const int lane = tid & 63;
    const int w    = tid >> 6;
    f16* wfeat = &feat[w * SLICE];

    const int unit  = blockIdx.x * 4 + w;   // 0..8191
    const int plane = unit >> 5;
    const int chunk = (unit >> 2) & 7;
    const int s     = unit & 3;
    const int r0    = chunk * 8;            // output rows (store-masked >= 62)
    const int c0    = s * 16;               // output cols

    // B fragments: 6 coalesced 16B loads (hoisted weight fold - R9 lesson:
    // the 48-scalar-load build cost ~20 us/grid when done per wave/block)
    f16x8 bfrag[3][2];
    #pragma unroll
    for (int q = 0; q < 6; ++q)
        bfrag[q >> 1][q & 1] = ws[q * 64 + lane];

    // zero the slice pad record (covers the kjp=1 col-17 edge A-read)
    if (lane < 2)
        *(f16x8*)&wfeat[2880 + lane * 8] = (f16x8){(f16)0.f,(f16)0.f,(f16)0.f,(f16)0.f,
                                                   (f16)0.f,(f16)0.f,(f16)0.f,(f16)0.f};

    const float g0    = grid_[0];
    const float inv_h = 1.0f / (grid_[1] - grid_[0]);
    const float* xp   = x + (size_t)plane * 4096;

    // ---- stage 1: features for the wave's 10x18 input tile
    #pragma unroll
    for (int it = 0; it < 3; ++it) {
        const int p = it * 64 + lane;
        if (p < 180) {
            const int row = p / 18;
            const int col = p - row * 18;
            int gy = r0 + row; gy = (gy < 64) ? gy : 63;   // clamped pixels feed
            int gx = c0 + col; gx = (gx < 64) ? gx : 63;   // only masked outputs
            const float xv = xp[gy * 64 + gx];

            const float si = xv / (1.0f + __expf(-xv));
            const float u  = (xv - g0) * inv_h;
            int j = (int)floorf(u);
            j = (j < 3) ? 3 : ((j > 7) ? 7 : j);
            const float tt  = u - (float)j;
            const float omt = 1.0f - tt;
            const float t2  = tt * tt;
            const float t3  = t2 * tt;
            const float c6  = 1.0f / 6.0f;
            const float bv0 = omt * omt * omt * c6;                        // slot j-2
            const float bv1 = (3.0f * t3 - 6.0f * t2 + 4.0f) * c6;         // slot j-1
            const float bv2 = (-3.0f * t3 + 3.0f * t2 + 3.0f * tt + 1.0f) * c6; // j
            const float bv3 = t3 * c6;                                     // slot j+1

            f16x8 r0v, r1v;
            r0v[0] = (f16)si;                    // slot 0 = silu
            #pragma unroll
            for (int f = 1; f < 8; ++f) {        // slots 1..7 branchless select
                float val = 0.0f;
                val = (f == j - 2) ? bv0 : val;
                val = (f == j - 1) ? bv1 : val;
                val = (f == j)     ? bv2 : val;
                val = (f == j + 1) ? bv3 : val;
                r0v[f] = (f16)val;
            }
            r1v[0] = (f16)((8 == j + 1) ? bv3 : 0.0f);       // slot 8
            #pragma unroll
            for (int f = 1; f < 8; ++f) r1v[f] = (f16)0.f;   // slots 9..15

            f16* fp = &wfeat[p * 16];
            *(f16x8*)fp       = r0v;
            *(f16x8*)(fp + 8) = r1v;
        }
    }
    // no barrier: wave reads only its own LDS writes (lgkmcnt ordering)

    // ---- stage 2: 8 output rows x 16 cols x 8 v via 6 MFMAs/row
    const int mI    = lane & 15;    // A row = out col; D col = v (same bits)
    const int kb    = lane >> 4;
    const int nn    = mI;
    const int khalf = kb & 1;
    const int cAdd  = kb >> 1;
    const int aBase = (mI + cAdd) * 16 + khalf * 8;

    f16x8 af[3][2];                 // rolling A rows (row r at af[r % 3])
    #pragma unroll
    for (int kjp = 0; kjp < 2; ++kjp) {
        af[0][kjp] = *(const f16x8*)&wfeat[aBase + kjp * 32 + 0 * 288];
        af[1][kjp] = *(const f16x8*)&wfeat[aBase + kjp * 32 + 1 * 288];
    }

    #pragma unroll
    for (int i = 0; i < 8; ++i) {
        #pragma unroll
        for (int kjp = 0; kjp < 2; ++kjp)
            af[(i + 2) % 3][kjp] =
                *(const f16x8*)&wfeat[aBase + kjp * 32 + (i + 2) * 288];

        f32x4 acc = {0.f, 0.f, 0.f, 0.f};
        #pragma unroll
        for (int ki = 0; ki < 3; ++ki)
            #pragma unroll
            for (int kjp = 0; kjp < 2; ++kjp)
                acc = __builtin_amdgcn_mfma_f32_16x16x32_f16(
                          af[(i + ki) % 3][kjp], bfrag[ki][kjp], acc, 0, 0, 0);

        const int ho = r0 + i;
        if (nn < 8 && ho < HO) {
            const int cb = c0 + kb * 4;
            float* po = out + ((size_t)(plane * 8 + nn) * (HO * WO)) + ho * WO + cb;
            if (cb + 3 < WO) {
                float2 lo = {acc[0], acc[1]};
                float2 hi = {acc[2], acc[3]};
                *(float2*)po       = lo;
                *(float2*)(po + 2) = hi;
            } else {
                #pragma unroll
                for (int q = 0; q < 4; ++q)
                    if (cb + q < WO) po[q] = acc[q];
            }
        }
    }
}

extern "C" void kernel_launch(void* const* d_in, const int* in_sizes, int n_in,
                              void* d_out, int out_size, void* d_ws, size_t ws_size,
                              hipStream_t stream) {
    const float* x    = (const float*)d_in[0];
    const float* grid = (const float*)d_in[1];
    const float* bw   = (const float*)d_in[2];
    const float* sw   = (const float*)d_in[3];
    const float* sc   = (const float*)d_in[4];
    float* out = (float*)d_out;
    f16x8* ws  = (f16x8*)d_ws;

    kan_prep_fast<<<6, 64, 0, stream>>>(bw, sw, sc, ws);
    kan_main<<<2048, 256, 0, stream>>>(x, grid, ws, out);
}